// Round 16
// baseline (103.481 us; speedup 1.0000x reference)
//
#include <hip/hip_runtime.h>
#include <hip/hip_bf16.h>
#include <hip/hip_fp16.h>

// KAN harmonic-basis GEMM, v19: v16 compute + BN=64 -> 2 independent
// blocks/CU (cross-block overlap) at conserved per-CU cost.
// out[b,h] = sum_{d,f} basis(x[b,d])[f] * W[d,f,h] + sum_d b[d,h]
//
// f=0 + bias -> fp32 partials c_part[8][256], summed in GEMM epilogue.
// f=1..10    -> f16 MFMA GEMM, M=16384, N=256, K=2560.
//
// v19 (v18 regressed -> revert to v16 skeleton. v16 @ ~35us runs 1 block/CU:
// its barrier/wait bubbles have nothing to fill them. BM=128 x BN=64 gives
// 512 blocks = 2 blocks/CU with per-CU totals CONSERVED: DMA 2x327KB = 655KB
// (same), LDS-read insts 16w x 160 = 2560 b128 (same; 2-i reuse kept), MFMA
// same. Trig VALU doubles (+~4us on a small term). The two blocks are NOT
// barrier-synced with each other -> block A's wait overlaps block B's
// compute (the v8 mechanism v14 traded away). v11's occupancy-null was
// phase-locked waves in ONE barrier domain; these are independent domains):
//   - 8 waves = wr(4) x wc(2); per wave 32 rows (2 i-frags) x 32 cols
//     (2 j-frags). VGPR working set ~90-100 -> __launch_bounds__(512,4) safe
//     (v10's spill was a 160+ set). Guard: WRITE_SIZE must stay ~16.4MB.
//   - 5-slot ring x 8KB (2-kt phases), 40KB/block, 80KB/CU for 2 blocks.
//     Stage = 1 global_load_lds per wave per phase (8 chunks: c = wave,
//     ktl = c>>2, f = c&3). v16's issue->wait->barrier->compute order.
//   - vmcnt audit (1 load/stage; x4 at q==2): steady q0: enter {S(p),S(p+1),
//     S(p+2)}=3, +S(p+3)=4, vmcnt(3) retires S(p). q1: 3,+1=4, wait 3.
//     q2: enter 3, +x4+S=8, vmcnt(7) retires S(p). q3: enter 7, +1=8,
//     vmcnt(7) retires S(p+1). q4: enter 7, +1=8, vmcnt(3) retires
//     S(p+2)+x4 (x done before next q0 sincos). Prologue x4+S0..2=7; dt0 q0
//     issues S3->8, vmcnt(3) retires x4+S0. Waits: 3,3,7,7,3.
//   - hw v_sin/v_cos, f16-resident state feeding mfma_f32_16x16x32_f16
//     directly, f16 B (all v16-verified, absmax 0.25).

#define BDIM 16384
#define DDIM 256
#define HOUT 256
#define NKT  80
#define BM 128
#define BN 64

typedef _Float16 halfx8 __attribute__((ext_vector_type(8)));
typedef float floatx4 __attribute__((ext_vector_type(4)));

__device__ __forceinline__ unsigned short f2h(float f) {
    union { _Float16 h; unsigned short u; } v;
    v.h = (_Float16)f;
    return v.u;
}

#define INV2PI 0.15915494309189535f

__device__ __forceinline__ void hwsincos(float x, float* s, float* c) {
    const float r = x * INV2PI;      // revolutions; |r| < 1 for N(0,1) inputs
    float sv, cv;
    asm("v_sin_f32 %0, %1" : "=v"(sv) : "v"(r));
    asm("v_cos_f32 %0, %1" : "=v"(cv) : "v"(r));
    *s = sv; *c = cv;
}

// grid 328 x 256 threads.
// blocks [0,320): kt = bid>>2, sub = bid&3:
//   Wfrag[kt][n=t][dd = sub*8 .. +8] = f16(W[dtile*32+dd][kt%10+1][n])
// blocks [320,328): p = bid-320; c_part[p][h] = sum_{d in p*32..+32} W[d][0][h]+b[d][h]
__global__ void prep_kernel(const float* __restrict__ W, const float* __restrict__ bias,
                            unsigned short* __restrict__ Wfrag, float* __restrict__ c_part) {
    const int bid = blockIdx.x;
    const int t = threadIdx.x;
    if (bid < 4 * NKT) {
        const int kt = bid >> 2;
        const int sub = bid & 3;
        const int dtile = kt / 10;
        const int f = kt - dtile * 10 + 1;
        const int d0 = dtile * 32 + sub * 8;
        const float* wsrc = W + ((size_t)d0 * 11 + f) * 256 + t;
        union { unsigned short s[8]; int4 v; } buf;
#pragma unroll
        for (int dd = 0; dd < 8; ++dd)
            buf.s[dd] = f2h(wsrc[(size_t)dd * 11 * 256]);
        *(int4*)(Wfrag + ((size_t)kt * 256 + t) * 32 + sub * 8) = buf.v;
    } else {
        const int p = bid - 4 * NKT;
        float acc = 0.f;
#pragma unroll
        for (int dd = 0; dd < 32; ++dd) {
            const int d = p * 32 + dd;
            acc += W[(size_t)(d * 11) * 256 + t] + bias[(size_t)d * 256 + t];
        }
        c_part[p * 256 + t] = acc;
    }
}

__global__ __launch_bounds__(512, 4)
void kan_gemm(const float* __restrict__ x, const unsigned short* __restrict__ Wfrag,
              const float* __restrict__ c_part, float* __restrict__ out) {
    // 5-slot ring of 8KB phases = 40,960 B -> 2 blocks/CU.
    __shared__ unsigned short Bs[5][2 * 4 * 512];

    const int t = threadIdx.x;
    const int m0 = blockIdx.x * BM;
    const int h0 = blockIdx.y * BN;

    const int lane = t & 63;
    const int wave = t >> 6;         // 0..7
    const int wr = wave >> 1;        // row quarter (32 rows)
    const int wc = wave & 1;         // col half (32 cols)
    const int l15 = lane & 15;
    const int koff = lane >> 4;

    floatx4 acc[2][2];
#pragma unroll
    for (int i = 0; i < 2; ++i)
#pragma unroll
        for (int j = 0; j < 2; ++j)
            acc[i][j] = (floatx4){0.f, 0.f, 0.f, 0.f};

    // lane's x rows: i=0 -> m0 + wr*32 + l15, i=1 -> +16; d-slots koff*8..+8
    const float* xr0 = x + (size_t)(m0 + wr * 32 + l15) * DDIM + koff * 8;

    // ---- prologue: x (4 loads) FIRST, then stages S0,S1,S2 (3 loads) ----
    float4 xn[4];
    xn[0] = *(const float4*)(xr0 + 0);
    xn[1] = *(const float4*)(xr0 + 4);
    xn[2] = *(const float4*)(xr0 + 16 * DDIM + 0);
    xn[3] = *(const float4*)(xr0 + 16 * DDIM + 4);

#pragma unroll
    for (int p = 0; p < 3; ++p) {
        const int c = wave;              // 8 chunks, 1 per wave
        const int ktl = c >> 2;
        const int f = c & 3;
        const unsigned short* g = Wfrag + (size_t)(p * 2 + ktl) * 8192
                                + (h0 + f * 16 + l15) * 32 + koff * 8;
        __builtin_amdgcn_global_load_lds((const void*)g,
            (void*)(&Bs[p][0] + c * 512), 16, 0, 0);
    }

    // f16-resident harmonic state: pair p holds elems {2p,2p+1};
    // p 0..3 -> i=0 (d-slots koff*8+0..7), p 4..7 -> i=1.
    __half2 s1h[8], c1h[8], skh[8], ckh[8];

#pragma unroll 1
    for (int dt = 0; dt < 8; ++dt) {
#pragma unroll
        for (int q = 0; q < 5; ++q) {
            // phase p = dt*5 + q; compute slot = q; write slot = (q+3)%5.

            // x prefetch for next dtile at q==2 (before stage issue).
            if (q == 2) {
                const int dn = (dt < 7) ? dt + 1 : 7;
                xn[0] = *(const float4*)(xr0 + dn * 32 + 0);
                xn[1] = *(const float4*)(xr0 + dn * 32 + 4);
                xn[2] = *(const float4*)(xr0 + 16 * DDIM + dn * 32 + 0);
                xn[3] = *(const float4*)(xr0 + 16 * DDIM + dn * 32 + 4);
            }

            // ---- issue stage(p+3) into slot (q+3)%5 (clamped tail) ----
            {
                int pt = dt * 5 + q + 3;
                if (pt > 39) pt = 39;
                const int c = wave;
                const int ktl = c >> 2;
                const int f = c & 3;
                const unsigned short* g = Wfrag + (size_t)(pt * 2 + ktl) * 8192
                                        + (h0 + f * 16 + l15) * 32 + koff * 8;
                __builtin_amdgcn_global_load_lds((const void*)g,
                    (void*)(&Bs[(q + 3) % 5][0] + c * 512), 16, 0, 0);
            }

            // ---- counted wait (audited: 3,3,7,7,3) + publish barrier ----
            __builtin_amdgcn_sched_barrier(0);
            if (q == 2 || q == 3) {
                asm volatile("s_waitcnt vmcnt(7)" ::: "memory");
            } else {
                asm volatile("s_waitcnt vmcnt(3)" ::: "memory");
            }
            __builtin_amdgcn_s_barrier();
            __builtin_amdgcn_sched_barrier(0);

            if (q == 0) {
                // ---- dtile start: hw sincos of 16 elems -> f16 state ----
#pragma unroll
                for (int p = 0; p < 8; ++p) {
                    float s0, c0, s1, c1;
                    const float xv0 = ((const float*)&xn[p >> 1])[(p & 1) * 2];
                    const float xv1 = ((const float*)&xn[p >> 1])[(p & 1) * 2 + 1];
                    hwsincos(xv0, &s0, &c0);
                    hwsincos(xv1, &s1, &c1);
                    const __half2 sh = __floats2half2_rn(s0, s1);
                    const __half2 ch = __floats2half2_rn(c0, c1);
                    s1h[p] = sh; c1h[p] = ch;
                    skh[p] = sh; ckh[p] = ch;
                }
            }

            // ---- compute 2 kt (harmonic q+1: sin then cos); A = state direct ----
#pragma unroll
            for (int s = 0; s < 2; ++s) {
                union { __half2 h2[4]; halfx8 v; } a0, a1;
                if (s == 0) {
#pragma unroll
                    for (int p = 0; p < 4; ++p) { a0.h2[p] = skh[p]; a1.h2[p] = skh[p + 4]; }
                } else {
#pragma unroll
                    for (int p = 0; p < 4; ++p) { a0.h2[p] = ckh[p]; a1.h2[p] = ckh[p + 4]; }
                }

                // this wc's 2 col-chunks (f = wc*2, wc*2+1)
                const unsigned short* fb = &Bs[q][(s * 4 + wc * 2) * 512 + lane * 8];
                const halfx8 b0 = *(const halfx8*)(fb);
                const halfx8 b1 = *(const halfx8*)(fb + 512);

                acc[0][0] = __builtin_amdgcn_mfma_f32_16x16x32_f16(a0.v, b0, acc[0][0], 0, 0, 0);
                acc[1][0] = __builtin_amdgcn_mfma_f32_16x16x32_f16(a1.v, b0, acc[1][0], 0, 0, 0);
                acc[0][1] = __builtin_amdgcn_mfma_f32_16x16x32_f16(a0.v, b1, acc[0][1], 0, 0, 0);
                acc[1][1] = __builtin_amdgcn_mfma_f32_16x16x32_f16(a1.v, b1, acc[1][1], 0, 0, 0);

                // advance harmonic k -> k+1 after the cos emit (except k=5):
                // ns = sk*c1 + ck*s1 ; nc = ck*c1 - sk*s1 (packed fp16)
                if (s == 1 && q < 4) {
#pragma unroll
                    for (int p = 0; p < 8; ++p) {
                        const __half2 t0 = __hmul2(ckh[p], s1h[p]);
                        const __half2 t1 = __hmul2(skh[p], s1h[p]);
                        const __half2 ns = __hfma2(skh[p], c1h[p], t0);
                        const __half2 nc = __hfma2(ckh[p], c1h[p], __hneg2(t1));
                        skh[p] = ns;
                        ckh[p] = nc;
                    }
                }
            }
        }
    }

    // drain redundant tail DMAs
    asm volatile("s_waitcnt vmcnt(0)" ::: "memory");

    // ---- epilogue: C/D layout col=lane&15, row=(lane>>4)*4+reg ----
    float cj[2];
#pragma unroll
    for (int j = 0; j < 2; ++j) {
        const int col = h0 + wc * 32 + j * 16 + l15;
        float s = 0.f;
#pragma unroll
        for (int q = 0; q < 8; ++q) s += c_part[q * 256 + col];
        cj[j] = s;
    }
#pragma unroll
    for (int i = 0; i < 2; ++i) {
        const int row0 = m0 + wr * 32 + i * 16 + koff * 4;
#pragma unroll
        for (int j = 0; j < 2; ++j) {
            const int col = h0 + wc * 32 + j * 16 + l15;
#pragma unroll
            for (int r = 0; r < 4; ++r)
                out[(size_t)(row0 + r) * HOUT + col] = acc[i][j][r] + cj[j];
        }
    }
}

extern "C" void kernel_launch(void* const* d_in, const int* in_sizes, int n_in,
                              void* d_out, int out_size, void* d_ws, size_t ws_size,
                              hipStream_t stream) {
    const float* x = (const float*)d_in[0];
    const float* W = (const float*)d_in[1];
    const float* b = (const float*)d_in[2];
    float* out = (float*)d_out;

    unsigned short* Wfrag = (unsigned short*)d_ws;                      // 1,310,720 B
    float* c_part = (float*)((char*)d_ws + (size_t)NKT * 256 * 32 * 2); // 8 KB

    prep_kernel<<<4 * NKT + 8, 256, 0, stream>>>(W, b, Wfrag, c_part);
    kan_gemm<<<dim3(BDIM / BM, HOUT / BN), 512, 0, stream>>>(x, Wfrag, c_part, out);
}